// Round 1
// baseline (70.101 us; speedup 1.0000x reference)
//
#include <hip/hip_runtime.h>
#include <math.h>

#define N 1024
#define D 128
#define TJ 64
#define MAXNORM 0.996f
#define MINN 1e-15f

__device__ __forceinline__ float wave_sum(float v) {
#pragma unroll
    for (int o = 32; o > 0; o >>= 1) v += __shfl_xor(v, o, 64);
    return v;
}

// block of 128 threads (2 waves)
__device__ __forceinline__ float bsum128(float v, float* s2) {
    v = wave_sum(v);
    int wid = threadIdx.x >> 6;
    __syncthreads();
    if ((threadIdx.x & 63) == 0) s2[wid] = v;
    __syncthreads();
    return s2[0] + s2[1];
}

__device__ __forceinline__ float artanhf_clip(float x) {
    x = fminf(fmaxf(x, -1.0f + 1e-7f), 1.0f - 1e-7f);
    return 0.5f * logf((1.0f + x) / (1.0f - x));
}

// ---- kernel 0: hyperbolic bias = proj(expmap0(bias)), plus its squared norm
__global__ __launch_bounds__(128) void k_bias(const float* __restrict__ bias,
                                              float* __restrict__ hb,
                                              float* __restrict__ hby2) {
    __shared__ float s2[2];
    int t = threadIdx.x;
    float b = bias[t];
    float n2 = bsum128(b * b, s2);
    float n = fmaxf(sqrtf(n2), MINN);
    float v = tanhf(n) * b / n;
    float vn2 = bsum128(v * v, s2);
    float vn = fmaxf(sqrtf(vn2), MINN);
    if (vn > MAXNORM) v = v / vn * MAXNORM;
    hb[t] = v;
    float y2 = bsum128(v * v, s2);
    if (t == 0) *hby2 = y2;
}

// ---- kernel 0b: transpose W (d_out,d_in) -> Wt (d_in,d_out) for coalesced reads
__global__ __launch_bounds__(128) void k_transpose(const float* __restrict__ Wm,
                                                   float* __restrict__ Wt) {
    int k = blockIdx.x;   // input-dim index
    int o = threadIdx.x;  // output-dim index
    Wt[k * D + o] = Wm[o * D + k];
}

// ---- kernel 1: per row: mv = proj(mobius_matvec(W,x)); h = proj(mobius_add(mv,hb));
//                scalars h2, sL = fac*(h.wl), sR = fac*(h.wr)
__global__ __launch_bounds__(128) void k_row(const float* __restrict__ x,
                                             const float* __restrict__ Wt,
                                             const float* __restrict__ hb,
                                             const float* __restrict__ hby2,
                                             const float* __restrict__ attw,
                                             float* __restrict__ h,
                                             float* __restrict__ h2o,
                                             float* __restrict__ sLo,
                                             float* __restrict__ sRo) {
    __shared__ float s2[2];
    __shared__ float xs[D];
    const int i = blockIdx.x;
    const int t = threadIdx.x;

    float xv = x[(size_t)i * D + t];
    xs[t] = xv;
    float xn2 = bsum128(xv * xv, s2);  // barrier inside also publishes xs
    float xn = fmaxf(sqrtf(xn2), MINN);

    // mx[t] = sum_k xs[k] * W[t][k] = sum_k xs[k] * Wt[k][t]  (coalesced)
    float mx = 0.f;
#pragma unroll 8
    for (int k = 0; k < D; ++k) mx += xs[k] * Wt[k * D + t];

    float mxn2 = bsum128(mx * mx, s2);
    float mxn = fmaxf(sqrtf(mxn2), MINN);
    float sc = tanhf(mxn / xn * artanhf_clip(xn)) / mxn;
    float res = sc * mx;
    // proj
    float rn2 = bsum128(res * res, s2);
    float rn = fmaxf(sqrtf(rn2), MINN);
    if (rn > MAXNORM) res = res / rn * MAXNORM;

    // mobius_add(res, hb)
    float hbv = hb[t];
    float x2 = bsum128(res * res, s2);
    float xy = bsum128(res * hbv, s2);
    float y2 = *hby2;
    float den = fmaxf(1.f + 2.f * xy + x2 * y2, MINN);
    float hp = ((1.f + 2.f * xy + y2) * res + (1.f - x2) * hbv) / den;
    // proj
    float hn2 = bsum128(hp * hp, s2);
    float hn = fmaxf(sqrtf(hn2), MINN);
    if (hn > MAXNORM) hp = hp / hn * MAXNORM;

    float h2 = bsum128(hp * hp, s2);
    float hnn = fmaxf(sqrtf(h2), MINN);
    float fac = artanhf_clip(hnn) / hnn;
    float dwl = bsum128(hp * attw[t], s2);
    float dwr = bsum128(hp * attw[D + t], s2);

    h[(size_t)i * D + t] = hp;
    if (t == 0) {
        h2o[i] = h2;
        sLo[i] = fac * dwl;
        sRo[i] = fac * dwr;
    }
}

// ---- kernel 2: pairwise scalars + aggregation + expmap/proj epilogue.
// 128 threads = 2 waves; wave w handles row i = blockIdx.x*2 + w.
// j processed in tiles of TJ=64 rows staged in LDS (stride 132 floats).
__global__ __launch_bounds__(128) void k_agg(const float* __restrict__ h,
                                             const float* __restrict__ h2a,
                                             const float* __restrict__ sLa,
                                             const float* __restrict__ sRa,
                                             const float* __restrict__ adj,
                                             const float* __restrict__ attb_p,
                                             float* __restrict__ out) {
    __shared__ float4 tile4[TJ * 33];           // 64 rows x 132 floats (pad 4)
    __shared__ __align__(16) float his[2][D];
    __shared__ float coeff[2][TJ];

    const int t = threadIdx.x;
    const int w = t >> 6;
    const int l = t & 63;
    const int i0 = blockIdx.x * 2;
    const int i = i0 + w;

    his[0][t] = h[(size_t)i0 * D + t];
    his[1][t] = h[(size_t)(i0 + 1) * D + t];

    const float h2_i = h2a[i];
    const float sL_i = sLa[i];
    const float attb = attb_p[0];
    const float B = 1.f - h2_i;                 // mobius num coeff (unclipped)
    const float cA = fmaxf(B, MINN);            // 2/lambda_i (clipped)

    float sAcc = 0.f;       // sum_j w_ij * alpha_ij (partial over this lane's j)
    float accB0 = 0.f;      // sum_j (w*beta)_ij * h_j[l]
    float accB1 = 0.f;      // sum_j (w*beta)_ij * h_j[l+64]

    const float4* his4 = (const float4*)(&his[w][0]);
    const float* tile = (const float*)tile4;

    for (int jb = 0; jb < N; jb += TJ) {
        __syncthreads();
        // cooperative tile load: TJ x D floats, coalesced float4
#pragma unroll
        for (int r = 0; r < 16; ++r) {
            int f = t + 128 * r;
            int row = f >> 5;   // 32 float4 per row
            int c4 = f & 31;
            tile4[row * 33 + c4] =
                *(const float4*)(h + (size_t)(jb + row) * D + c4 * 4);
        }
        __syncthreads();

        const int j = jb + l;
        // dot_ij = h_i . h_j
        float dot = 0.f;
        const float4* trow = tile4 + l * 33;
#pragma unroll 8
        for (int k4 = 0; k4 < 32; ++k4) {
            float4 a = his4[k4];
            float4 b = trow[k4];
            dot += a.x * b.x + a.y * b.y + a.z * b.z + a.w * b.w;
        }
        float h2_j = h2a[j];
        float A = 1.f - 2.f * dot + h2_j;
        float den = fmaxf(1.f - 2.f * dot + h2_i * h2_j, MINN);
        float p = -A / den;
        float q = B / den;
        float n2 = p * p * h2_i + 2.f * p * q * dot + q * q * h2_j;
        float nrm = fmaxf(sqrtf(fmaxf(n2, 0.f)), MINN);
        float coefc = cA * artanhf_clip(nrm) / nrm;
        float alpha = coefc * p;
        float beta = coefc * q;
        float logit = sL_i + sRa[j] + attb;
        float sig = 1.f / (1.f + expf(-logit));
        float wgt = adj[(size_t)i * N + j] * sig;
        sAcc += wgt * alpha;
        coeff[w][l] = wgt * beta;
        __syncthreads();

        // accB[k] += sum_t2 coeff[t2] * h_{jb+t2}[k]; lane l owns k=l and k=l+64
#pragma unroll 8
        for (int t2 = 0; t2 < TJ; ++t2) {
            float c = coeff[w][t2];
            accB0 += c * tile[t2 * 132 + l];
            accB1 += c * tile[t2 * 132 + l + 64];
        }
    }

    // finish: support u = sA*h_i + accB
    float sA = wave_sum(sAcc);
    float hi0 = his[w][l], hi1 = his[w][l + 64];
    float u0 = sA * hi0 + accB0;
    float u1 = sA * hi1 + accB1;

    // expmap(h_i, u): second = tanh(lam*n/2)*u/n ; then mobius_add(h_i, second)
    float u2 = wave_sum(u0 * u0 + u1 * u1);
    float un = fmaxf(sqrtf(u2), MINN);
    float lam = 2.f / cA;
    float th = tanhf(0.5f * lam * un);
    float s0 = th * u0 / un, s1 = th * u1 / un;
    float y2 = wave_sum(s0 * s0 + s1 * s1);
    float xy = wave_sum(hi0 * s0 + hi1 * s1);
    float x2 = h2_i;
    float den2 = fmaxf(1.f + 2.f * xy + x2 * y2, MINN);
    float c1 = (1.f + 2.f * xy + y2) / den2;
    float c2 = (1.f - x2) / den2;
    float hp0 = c1 * hi0 + c2 * s0;
    float hp1 = c1 * hi1 + c2 * s1;
    // proj
    float hn2 = wave_sum(hp0 * hp0 + hp1 * hp1);
    float hn = fmaxf(sqrtf(hn2), MINN);
    float scl = (hn > MAXNORM) ? (MAXNORM / hn) : 1.f;
    hp0 *= scl;
    hp1 *= scl;
    float n3 = fminf(hn, MAXNORM);
    n3 = fmaxf(n3, MINN);
    // expmap0 + final proj (tanh(n3) < MAXNORM always, but keep the check)
    float fac = tanhf(n3) / n3;
    float o0 = fac * hp0, o1 = fac * hp1;
    float onrm = tanhf(n3);
    if (onrm > MAXNORM) {
        float s = MAXNORM / onrm;
        o0 *= s;
        o1 *= s;
    }
    out[(size_t)i * D + l] = o0;
    out[(size_t)i * D + l + 64] = o1;
}

extern "C" void kernel_launch(void* const* d_in, const int* in_sizes, int n_in,
                              void* d_out, int out_size, void* d_ws, size_t ws_size,
                              hipStream_t stream) {
    const float* x = (const float*)d_in[0];
    const float* adj = (const float*)d_in[1];
    const float* Wm = (const float*)d_in[2];
    const float* bias = (const float*)d_in[3];
    const float* attw = (const float*)d_in[4];
    const float* attb = (const float*)d_in[5];
    float* out = (float*)d_out;

    float* ws = (float*)d_ws;
    float* hb = ws;                    // 128
    float* hby2 = ws + 128;            // 1
    float* Wt = ws + 256;              // 16384
    float* h = Wt + D * D;             // 131072 (16B-aligned offset)
    float* h2a = h + (size_t)N * D;    // 1024
    float* sL = h2a + N;               // 1024
    float* sR = sL + N;                // 1024

    hipLaunchKernelGGL(k_bias, dim3(1), dim3(128), 0, stream, bias, hb, hby2);
    hipLaunchKernelGGL(k_transpose, dim3(D), dim3(128), 0, stream, Wm, Wt);
    hipLaunchKernelGGL(k_row, dim3(N), dim3(128), 0, stream, x, Wt, hb, hby2,
                       attw, h, h2a, sL, sR);
    hipLaunchKernelGGL(k_agg, dim3(N / 2), dim3(128), 0, stream, h, h2a, sL, sR,
                       adj, attb, out);
}

// Round 2
// 47.926 us; speedup vs baseline: 1.4627x; 1.4627x over previous
//
#include <hip/hip_runtime.h>
#include <math.h>

#define N 1024
#define D 128
#define TJ 64
#define NS 4
#define SLICE (N / NS)   // 256
#define NTILE (SLICE / TJ) // 4
#define MAXNORM 0.996f
#define MINN 1e-15f

__device__ __forceinline__ float wave_sum(float v) {
#pragma unroll
    for (int o = 32; o > 0; o >>= 1) v += __shfl_xor(v, o, 64);
    return v;
}

__device__ __forceinline__ float artanh_fast(float x) {
    x = fminf(fmaxf(x, -1.0f + 1e-7f), 1.0f - 1e-7f);
    return 0.5f * __logf(__fdividef(1.0f + x, 1.0f - x));
}

// ---- kernel 0: block 0 = hyperbolic bias (1 wave); blocks 1..128 = W transpose
__global__ __launch_bounds__(128) void k_prep(const float* __restrict__ bias,
                                              const float* __restrict__ Wm,
                                              float* __restrict__ hb,
                                              float* __restrict__ hby2,
                                              float* __restrict__ Wt) {
    const int t = threadIdx.x;
    if (blockIdx.x > 0) {
        int k = blockIdx.x - 1;
        Wt[k * D + t] = Wm[t * D + k];
        return;
    }
    if (t >= 64) return;
    float2 b = *(const float2*)(bias + 2 * t);
    float n2 = wave_sum(b.x * b.x + b.y * b.y);
    float n = fmaxf(sqrtf(n2), MINN);
    float s = tanhf(n) / n;
    float2 v = make_float2(s * b.x, s * b.y);
    float vn2 = wave_sum(v.x * v.x + v.y * v.y);
    float vn = fmaxf(sqrtf(vn2), MINN);
    if (vn > MAXNORM) { float sc = MAXNORM / vn; v.x *= sc; v.y *= sc; }
    *(float2*)(hb + 2 * t) = v;
    float y2 = wave_sum(v.x * v.x + v.y * v.y);
    if (t == 0) *hby2 = y2;
}

// ---- kernel 1: one wave per row; lane l owns dims (2l, 2l+1)
__global__ __launch_bounds__(128) void k_row(const float* __restrict__ x,
                                             const float* __restrict__ Wt,
                                             const float* __restrict__ hb,
                                             const float* __restrict__ hby2,
                                             const float* __restrict__ attw,
                                             float* __restrict__ h,
                                             float* __restrict__ h2o,
                                             float* __restrict__ sLo,
                                             float* __restrict__ sRo) {
    __shared__ float xs[2][D];
    const int w = threadIdx.x >> 6, l = threadIdx.x & 63;
    const int i = blockIdx.x * 2 + w;

    float2 xv = *(const float2*)(x + (size_t)i * D + 2 * l);
    *(float2*)&xs[w][2 * l] = xv;
    __syncthreads();

    float xn2 = wave_sum(xv.x * xv.x + xv.y * xv.y);
    float xn = fmaxf(sqrtf(xn2), MINN);

    float mx0 = 0.f, mx1 = 0.f;
#pragma unroll 8
    for (int k = 0; k < D; ++k) {
        float xk = xs[w][k];
        float2 wv = *(const float2*)(Wt + k * D + 2 * l);
        mx0 += xk * wv.x;
        mx1 += xk * wv.y;
    }

    float mxn2 = wave_sum(mx0 * mx0 + mx1 * mx1);
    float mxn = fmaxf(sqrtf(mxn2), MINN);
    float sc = tanhf(mxn / xn * artanh_fast(xn)) / mxn;
    float r0 = sc * mx0, r1 = sc * mx1;
    // proj
    float rn2 = wave_sum(r0 * r0 + r1 * r1);
    float rn = fmaxf(sqrtf(rn2), MINN);
    float sr = (rn > MAXNORM) ? (MAXNORM / rn) : 1.f;
    r0 *= sr; r1 *= sr;
    float x2 = rn2 * sr * sr;

    // mobius_add(r, hb)
    float2 hbv = *(const float2*)(hb + 2 * l);
    float xy = wave_sum(r0 * hbv.x + r1 * hbv.y);
    float y2 = *hby2;
    float den = fmaxf(1.f + 2.f * xy + x2 * y2, MINN);
    float ca = (1.f + 2.f * xy + y2) / den;
    float cb = (1.f - x2) / den;
    float hp0 = ca * r0 + cb * hbv.x;
    float hp1 = ca * r1 + cb * hbv.y;
    // proj
    float hn2 = wave_sum(hp0 * hp0 + hp1 * hp1);
    float hn = fmaxf(sqrtf(hn2), MINN);
    float sh = (hn > MAXNORM) ? (MAXNORM / hn) : 1.f;
    hp0 *= sh; hp1 *= sh;
    float h2 = hn2 * sh * sh;

    float hnn = fmaxf(sqrtf(h2), MINN);
    float fac = artanh_fast(hnn) / hnn;
    float dwl = wave_sum(hp0 * attw[2 * l] + hp1 * attw[2 * l + 1]);
    float dwr = wave_sum(hp0 * attw[D + 2 * l] + hp1 * attw[D + 2 * l + 1]);

    *(float2*)(h + (size_t)i * D + 2 * l) = make_float2(hp0, hp1);
    if (l == 0) {
        h2o[i] = h2;
        sLo[i] = fac * dwl;
        sRo[i] = fac * dwr;
    }
}

// ---- kernel 2: partial aggregation. grid (N/4, NS); 256 thr = 4 waves = 4 rows.
// wave w handles row i = bi*4+w over j-slice [s*SLICE, (s+1)*SLICE).
__global__ __launch_bounds__(256) void k_agg(const float* __restrict__ h,
                                             const float* __restrict__ h2a,
                                             const float* __restrict__ sLa,
                                             const float* __restrict__ sRa,
                                             const float* __restrict__ adj,
                                             const float* __restrict__ attb_p,
                                             float* __restrict__ partA,
                                             float* __restrict__ partB) {
    __shared__ float4 tile4[TJ * 33];              // 64 x 132 floats (pad)
    __shared__ __align__(16) float his[4][D];
    __shared__ float coeff[4][TJ];

    const int t = threadIdx.x, w = t >> 6, l = t & 63;
    const int bi = blockIdx.x, s = blockIdx.y;
    const int i = bi * 4 + w;

    *(float2*)&his[w][2 * l] = *(const float2*)(h + (size_t)i * D + 2 * l);

    const float h2_i = h2a[i];
    const float sL_i = sLa[i];
    const float attb = attb_p[0];
    const float B = 1.f - h2_i;
    const float cA = fmaxf(B, MINN);

    float sAcc = 0.f, accB0 = 0.f, accB1 = 0.f;
    const float4* his4 = (const float4*)his[w];
    const float* tile = (const float*)tile4;
    const int jb0 = s * SLICE;

    for (int tt = 0; tt < NTILE; ++tt) {
        const int jb = jb0 + tt * TJ;
        __syncthreads();
#pragma unroll
        for (int r = 0; r < 8; ++r) {
            int f = t + 256 * r;
            int row = f >> 5, c4 = f & 31;
            tile4[row * 33 + c4] =
                *(const float4*)(h + (size_t)(jb + row) * D + c4 * 4);
        }
        __syncthreads();

        const int j = jb + l;
        float dot = 0.f;
        const float4* trow = tile4 + l * 33;
#pragma unroll 8
        for (int k4 = 0; k4 < 32; ++k4) {
            float4 a = his4[k4], b = trow[k4];
            dot += a.x * b.x + a.y * b.y + a.z * b.z + a.w * b.w;
        }
        float h2_j = h2a[j];
        float den = fmaxf(1.f - 2.f * dot + h2_i * h2_j, MINN);
        float p = __fdividef(-(1.f - 2.f * dot + h2_j), den);
        float q = __fdividef(B, den);
        float n2 = p * p * h2_i + 2.f * p * q * dot + q * q * h2_j;
        float nrm = fmaxf(sqrtf(fmaxf(n2, 0.f)), MINN);
        float coefc = cA * __fdividef(artanh_fast(nrm), nrm);
        float alpha = coefc * p, beta = coefc * q;
        float logit = sL_i + sRa[j] + attb;
        float sig = __fdividef(1.f, 1.f + __expf(-logit));
        float wgt = adj[(size_t)i * N + j] * sig;
        sAcc += wgt * alpha;
        coeff[w][l] = wgt * beta;
        __syncthreads();

#pragma unroll 8
        for (int t2 = 0; t2 < TJ; ++t2) {
            float c = coeff[w][t2];
            float2 hv = *(const float2*)(tile + t2 * 132 + 2 * l);
            accB0 += c * hv.x;
            accB1 += c * hv.y;
        }
    }

    float sA = wave_sum(sAcc);
    *(float2*)(partB + ((size_t)(s * N + i)) * D + 2 * l) =
        make_float2(accB0, accB1);
    if (l == 0) partA[s * N + i] = sA;
}

// ---- kernel 3: reduce partials + expmap/proj epilogue. 2 waves = 2 rows/block.
__global__ __launch_bounds__(128) void k_fin(const float* __restrict__ h,
                                             const float* __restrict__ h2a,
                                             const float* __restrict__ partA,
                                             const float* __restrict__ partB,
                                             float* __restrict__ out) {
    const int w = threadIdx.x >> 6, l = threadIdx.x & 63;
    const int i = blockIdx.x * 2 + w;

    float2 hi = *(const float2*)(h + (size_t)i * D + 2 * l);
    const float h2_i = h2a[i];

    float sA = 0.f, b0 = 0.f, b1 = 0.f;
#pragma unroll
    for (int s = 0; s < NS; ++s) {
        sA += partA[s * N + i];
        float2 p = *(const float2*)(partB + ((size_t)(s * N + i)) * D + 2 * l);
        b0 += p.x;
        b1 += p.y;
    }
    float u0 = sA * hi.x + b0, u1 = sA * hi.y + b1;

    float cA = fmaxf(1.f - h2_i, MINN);
    float u2 = wave_sum(u0 * u0 + u1 * u1);
    float un = fmaxf(sqrtf(u2), MINN);
    float lam = 2.f / cA;
    float th = tanhf(0.5f * lam * un);
    float s0 = th * u0 / un, s1 = th * u1 / un;
    float y2 = wave_sum(s0 * s0 + s1 * s1);
    float xy = wave_sum(hi.x * s0 + hi.y * s1);
    float den2 = fmaxf(1.f + 2.f * xy + h2_i * y2, MINN);
    float c1 = (1.f + 2.f * xy + y2) / den2;
    float c2 = (1.f - h2_i) / den2;
    float hp0 = c1 * hi.x + c2 * s0;
    float hp1 = c1 * hi.y + c2 * s1;
    float hn2 = wave_sum(hp0 * hp0 + hp1 * hp1);
    float hn = fmaxf(sqrtf(hn2), MINN);
    float scl = (hn > MAXNORM) ? (MAXNORM / hn) : 1.f;
    hp0 *= scl; hp1 *= scl;
    float n3 = fminf(fmaxf(hn, MINN), MAXNORM);
    float fac = tanhf(n3) / n3;
    float o0 = fac * hp0, o1 = fac * hp1;
    float onrm = tanhf(n3);
    if (onrm > MAXNORM) {
        float ss = MAXNORM / onrm;
        o0 *= ss; o1 *= ss;
    }
    *(float2*)(out + (size_t)i * D + 2 * l) = make_float2(o0, o1);
}

extern "C" void kernel_launch(void* const* d_in, const int* in_sizes, int n_in,
                              void* d_out, int out_size, void* d_ws, size_t ws_size,
                              hipStream_t stream) {
    const float* x = (const float*)d_in[0];
    const float* adj = (const float*)d_in[1];
    const float* Wm = (const float*)d_in[2];
    const float* bias = (const float*)d_in[3];
    const float* attw = (const float*)d_in[4];
    const float* attb = (const float*)d_in[5];
    float* out = (float*)d_out;

    float* ws = (float*)d_ws;
    float* hb = ws;                      // 128
    float* hby2 = ws + 128;              // 1 (pad to 256)
    float* Wt = ws + 256;                // 16384
    float* h = Wt + D * D;               // 131072
    float* h2a = h + (size_t)N * D;      // 1024
    float* sL = h2a + N;                 // 1024
    float* sR = sL + N;                  // 1024
    float* partA = sR + N;               // NS*N = 4096
    float* partB = partA + NS * N;       // NS*N*D = 524288 (2 MB)

    hipLaunchKernelGGL(k_prep, dim3(D + 1), dim3(128), 0, stream, bias, Wm, hb,
                       hby2, Wt);
    hipLaunchKernelGGL(k_row, dim3(N / 2), dim3(128), 0, stream, x, Wt, hb,
                       hby2, attw, h, h2a, sL, sR);
    hipLaunchKernelGGL(k_agg, dim3(N / 4, NS), dim3(256), 0, stream, h, h2a, sL,
                       sR, adj, attb, partA, partB);
    hipLaunchKernelGGL(k_fin, dim3(N / 2), dim3(128), 0, stream, h, h2a, partA,
                       partB, out);
}

// Round 3
// 29.832 us; speedup vs baseline: 2.3499x; 1.6066x over previous
//
#include <hip/hip_runtime.h>
#include <math.h>

#define N 1024
#define D 128
#define MAXNORM 0.996f
#define MINN 1e-15f

__device__ __forceinline__ float wave_sum(float v) {
#pragma unroll
    for (int o = 32; o > 0; o >>= 1) v += __shfl_xor(v, o, 64);
    return v;
}

__device__ __forceinline__ float artanh_fast(float x) {
    x = fminf(fmaxf(x, -1.0f + 1e-7f), 1.0f - 1e-7f);
    return 0.5f * __logf(__fdividef(1.0f + x, 1.0f - x));
}

// ---- kernel 0: block 0 = hyperbolic bias (1 wave); blocks 1..128 = W transpose
__global__ __launch_bounds__(128) void k_prep(const float* __restrict__ bias,
                                              const float* __restrict__ Wm,
                                              float* __restrict__ hb,
                                              float* __restrict__ hby2,
                                              float* __restrict__ Wt) {
    const int t = threadIdx.x;
    if (blockIdx.x > 0) {
        int k = blockIdx.x - 1;
        Wt[k * D + t] = Wm[t * D + k];
        return;
    }
    if (t >= 64) return;
    float2 b = *(const float2*)(bias + 2 * t);
    float n2 = wave_sum(b.x * b.x + b.y * b.y);
    float n = fmaxf(sqrtf(n2), MINN);
    float s = tanhf(n) / n;
    float2 v = make_float2(s * b.x, s * b.y);
    float vn2 = wave_sum(v.x * v.x + v.y * v.y);
    float vn = fmaxf(sqrtf(vn2), MINN);
    if (vn > MAXNORM) { float sc = MAXNORM / vn; v.x *= sc; v.y *= sc; }
    *(float2*)(hb + 2 * t) = v;
    float y2 = wave_sum(v.x * v.x + v.y * v.y);
    if (t == 0) *hby2 = y2;
}

// ---- kernel 1: one wave per row; lane l owns dims (2l, 2l+1)
__global__ __launch_bounds__(128) void k_row(const float* __restrict__ x,
                                             const float* __restrict__ Wt,
                                             const float* __restrict__ hb,
                                             const float* __restrict__ hby2,
                                             const float* __restrict__ attw,
                                             float* __restrict__ h,
                                             float* __restrict__ h2o,
                                             float* __restrict__ sLo,
                                             float* __restrict__ sRo) {
    __shared__ float xs[2][D];
    const int w = threadIdx.x >> 6, l = threadIdx.x & 63;
    const int i = blockIdx.x * 2 + w;

    float2 xv = *(const float2*)(x + (size_t)i * D + 2 * l);
    *(float2*)&xs[w][2 * l] = xv;
    __syncthreads();

    float xn2 = wave_sum(xv.x * xv.x + xv.y * xv.y);
    float xn = fmaxf(sqrtf(xn2), MINN);

    float mx0 = 0.f, mx1 = 0.f;
#pragma unroll 8
    for (int k = 0; k < D; ++k) {
        float xk = xs[w][k];
        float2 wv = *(const float2*)(Wt + k * D + 2 * l);
        mx0 += xk * wv.x;
        mx1 += xk * wv.y;
    }

    float mxn2 = wave_sum(mx0 * mx0 + mx1 * mx1);
    float mxn = fmaxf(sqrtf(mxn2), MINN);
    float sc = tanhf(mxn / xn * artanh_fast(xn)) / mxn;
    float r0 = sc * mx0, r1 = sc * mx1;
    float rn2 = wave_sum(r0 * r0 + r1 * r1);
    float rn = fmaxf(sqrtf(rn2), MINN);
    float sr = (rn > MAXNORM) ? (MAXNORM / rn) : 1.f;
    r0 *= sr; r1 *= sr;
    float x2 = rn2 * sr * sr;

    float2 hbv = *(const float2*)(hb + 2 * l);
    float xy = wave_sum(r0 * hbv.x + r1 * hbv.y);
    float y2 = *hby2;
    float den = fmaxf(1.f + 2.f * xy + x2 * y2, MINN);
    float ca = (1.f + 2.f * xy + y2) / den;
    float cb = (1.f - x2) / den;
    float hp0 = ca * r0 + cb * hbv.x;
    float hp1 = ca * r1 + cb * hbv.y;
    float hn2 = wave_sum(hp0 * hp0 + hp1 * hp1);
    float hn = fmaxf(sqrtf(hn2), MINN);
    float sh = (hn > MAXNORM) ? (MAXNORM / hn) : 1.f;
    hp0 *= sh; hp1 *= sh;
    float h2 = hn2 * sh * sh;

    float hnn = fmaxf(sqrtf(h2), MINN);
    float fac = artanh_fast(hnn) / hnn;
    float dwl = wave_sum(hp0 * attw[2 * l] + hp1 * attw[2 * l + 1]);
    float dwr = wave_sum(hp0 * attw[D + 2 * l] + hp1 * attw[D + 2 * l + 1]);

    *(float2*)(h + (size_t)i * D + 2 * l) = make_float2(hp0, hp1);
    if (l == 0) {
        h2o[i] = h2;
        sLo[i] = fac * dwl;
        sRo[i] = fac * dwr;
    }
}

// ---- kernel 2: sparse aggregation + epilogue. One block (4 waves) per row i.
__global__ __launch_bounds__(256) void k_agg(const float* __restrict__ h,
                                             const float* __restrict__ h2a,
                                             const float* __restrict__ sLa,
                                             const float* __restrict__ sRa,
                                             const float* __restrict__ adj,
                                             const float* __restrict__ attb_p,
                                             float* __restrict__ out) {
    __shared__ int lst[N];
    __shared__ int wcnt[4];
    __shared__ float accS[4][D];
    __shared__ float sAs[4];

    const int t = threadIdx.x, w = t >> 6, l = t & 63;
    const int i = blockIdx.x;
    const unsigned long long lt_mask = (1ull << l) - 1ull;

    // --- scan this wave's 256-column segment of adj row i (coalesced float4)
    float4 av = *(const float4*)(adj + (size_t)i * N + w * 256 + 4 * l);
    float ae[4] = {av.x, av.y, av.z, av.w};
    unsigned long long msk[4];
    int cnt = 0;
#pragma unroll
    for (int e = 0; e < 4; ++e) {
        msk[e] = __ballot(ae[e] != 0.0f);
        cnt += __popcll(msk[e]);
    }
    if (l == 0) wcnt[w] = cnt;
    __syncthreads();

    int base = 0;
#pragma unroll
    for (int ww = 0; ww < 4; ++ww)
        if (ww < w) base += wcnt[ww];
    const int tot = wcnt[0] + wcnt[1] + wcnt[2] + wcnt[3];

    int off = base;
#pragma unroll
    for (int e = 0; e < 4; ++e) {
        if (ae[e] != 0.0f) {
            int pos = __popcll(msk[e] & lt_mask);
            lst[off + pos] = w * 256 + 4 * l + e;
        }
        off += __popcll(msk[e]);
    }
    __syncthreads();

    // --- row-i state
    float2 hi = *(const float2*)(h + (size_t)i * D + 2 * l);
    const float h2_i = h2a[i];
    const float sL_i = sLa[i];
    const float attb = attb_p[0];
    const float B = 1.f - h2_i;
    const float cA = fmaxf(B, MINN);

    float sAcc = 0.f, accB0 = 0.f, accB1 = 0.f;

    for (int n = w; n < tot; n += 4) {
        const int j = lst[n];
        float2 hj = *(const float2*)(h + (size_t)j * D + 2 * l);
        float aval = adj[(size_t)i * N + j];
        float h2_j = h2a[j];
        float sR_j = sRa[j];
        float dot = wave_sum(hi.x * hj.x + hi.y * hj.y);
        float den = fmaxf(1.f - 2.f * dot + h2_i * h2_j, MINN);
        float p = __fdividef(-(1.f - 2.f * dot + h2_j), den);
        float q = __fdividef(B, den);
        float n2 = p * p * h2_i + 2.f * p * q * dot + q * q * h2_j;
        float nrm = fmaxf(sqrtf(fmaxf(n2, 0.f)), MINN);
        float coefc = cA * __fdividef(artanh_fast(nrm), nrm);
        float sig = __fdividef(1.f, 1.f + __expf(-(sL_i + sR_j + attb)));
        float wgt = aval * sig;
        sAcc += wgt * coefc * p;
        float wb = wgt * coefc * q;
        accB0 += wb * hj.x;
        accB1 += wb * hj.y;
    }

    accS[w][2 * l] = accB0;
    accS[w][2 * l + 1] = accB1;
    if (l == 0) sAs[w] = sAcc;
    __syncthreads();

    if (w != 0) return;

    float b0 = accS[0][2 * l] + accS[1][2 * l] + accS[2][2 * l] + accS[3][2 * l];
    float b1 = accS[0][2 * l + 1] + accS[1][2 * l + 1] + accS[2][2 * l + 1] +
               accS[3][2 * l + 1];
    float sA = sAs[0] + sAs[1] + sAs[2] + sAs[3];

    float u0 = sA * hi.x + b0, u1 = sA * hi.y + b1;

    float u2 = wave_sum(u0 * u0 + u1 * u1);
    float un = fmaxf(sqrtf(u2), MINN);
    float lam = 2.f / cA;
    float th = tanhf(0.5f * lam * un);
    float s0 = th * u0 / un, s1 = th * u1 / un;
    float y2 = wave_sum(s0 * s0 + s1 * s1);
    float xy = wave_sum(hi.x * s0 + hi.y * s1);
    float den2 = fmaxf(1.f + 2.f * xy + h2_i * y2, MINN);
    float c1 = (1.f + 2.f * xy + y2) / den2;
    float c2 = (1.f - h2_i) / den2;
    float hp0 = c1 * hi.x + c2 * s0;
    float hp1 = c1 * hi.y + c2 * s1;
    float hn2 = wave_sum(hp0 * hp0 + hp1 * hp1);
    float hn = fmaxf(sqrtf(hn2), MINN);
    float scl = (hn > MAXNORM) ? (MAXNORM / hn) : 1.f;
    hp0 *= scl; hp1 *= scl;
    float n3 = fminf(fmaxf(hn, MINN), MAXNORM);
    float fac = tanhf(n3) / n3;
    float o0 = fac * hp0, o1 = fac * hp1;
    float onrm = tanhf(n3);
    if (onrm > MAXNORM) {
        float ss = MAXNORM / onrm;
        o0 *= ss; o1 *= ss;
    }
    *(float2*)(out + (size_t)i * D + 2 * l) = make_float2(o0, o1);
}

extern "C" void kernel_launch(void* const* d_in, const int* in_sizes, int n_in,
                              void* d_out, int out_size, void* d_ws, size_t ws_size,
                              hipStream_t stream) {
    const float* x = (const float*)d_in[0];
    const float* adj = (const float*)d_in[1];
    const float* Wm = (const float*)d_in[2];
    const float* bias = (const float*)d_in[3];
    const float* attw = (const float*)d_in[4];
    const float* attb = (const float*)d_in[5];
    float* out = (float*)d_out;

    float* ws = (float*)d_ws;
    float* hb = ws;                      // 128
    float* hby2 = ws + 128;              // 1 (pad to 256)
    float* Wt = ws + 256;                // 16384
    float* h = Wt + D * D;               // 131072
    float* h2a = h + (size_t)N * D;      // 1024
    float* sL = h2a + N;                 // 1024
    float* sR = sL + N;                  // 1024

    hipLaunchKernelGGL(k_prep, dim3(D + 1), dim3(128), 0, stream, bias, Wm, hb,
                       hby2, Wt);
    hipLaunchKernelGGL(k_row, dim3(N / 2), dim3(128), 0, stream, x, Wt, hb,
                       hby2, attw, h, h2a, sL, sR);
    hipLaunchKernelGGL(k_agg, dim3(N), dim3(256), 0, stream, h, h2a, sL, sR,
                       adj, attb, out);
}